// Round 9
// baseline (146.764 us; speedup 1.0000x reference)
//
#include <hip/hip_runtime.h>
#include <hip/hip_bf16.h>
#include <cstdint>
#include <cstddef>

// out = (A2 @ E^T) @ W^T, A2[i,j] = a[i-j] lower-tri Toeplitz,
//   a[d] = (d/4096 + 1e-8)^0.2, a[0] = 1e-8^0.2
// gemm_a: T[i,e] = sum_{j<=i} a[i-j] * E[e,j]  (tri, split-j -> T0 + T1)
// gemm_b: out[i,v] = sum_e T0[i,e]*W[v,e] + sum_e T1[i,e]*W[v,e]
// Round 15: R8 established both GEMMs are staging/LDS-bandwidth-bound
// (~2600 cyc/step vs 320 cyc MFMA). Fix: feed cache-resident operands
// DIRECTLY to MFMA fragments, no LDS transit:
//  - gemm_a A-operand: Toeplitz band, 191 distinct values/tile. R's
//    reversed+replica layout makes every A-fragment 8 contiguous bf16 ->
//    one base pointer + imm offsets (L1-resident). A-staging deleted.
//  - gemm_b B-operand: W-panel/step = 16 KB, L1-fit, XCD-local. Direct
//    fragment loads via 4 row-pointers. W-staging deleted.
// LDS traffic per block-step halves (96 -> 48 KB); barrier drain covers
// half the loads; global path overlaps the DS pipe.

#define L_SER 4096
#define DEMB  1024
#define DV    1024

#define R_STRIDE 4224   // shift-replica stride of reversed a; 16B-aligned
#define R_O0     4096

typedef __bf16 bf16_t;
typedef __attribute__((ext_vector_type(8))) __bf16 bf16x8;
typedef __attribute__((ext_vector_type(4))) float f32x4;

// direct global->LDS async copy, 16B per lane (dest = uniform base + lane*16)
__device__ __forceinline__ void glds16(const bf16_t* g, bf16_t* l) {
    __builtin_amdgcn_global_load_lds(
        (const __attribute__((address_space(1))) unsigned int*)(const void*)g,
        (__attribute__((address_space(3))) unsigned int*)(void*)l,
        16, 0, 0);
}

// ---------------------------------------------------------------------------
// Fused prep: blocks [0,132) build R; [132,2180) convert E; [2180,2692) convert W.
// ---------------------------------------------------------------------------
__global__ void prep_kernel(const float* __restrict__ E, const float* __restrict__ W,
                            bf16_t* __restrict__ Eb, bf16_t* __restrict__ Wb,
                            bf16_t* __restrict__ R) {
    const int b = blockIdx.x;
    if (b < 132) {                       // 132*256 = 33792 = 8*4224 exact
        int idx = b * 256 + threadIdx.x;
        int s = idx / R_STRIDE;
        int x = idx - s * R_STRIDE;
        int d = R_O0 + s - x;
        float v = 0.0f;
        if (d >= 0 && d < L_SER)
            v = powf((d == 0) ? 1e-8f : ((float)d * (1.0f / (float)L_SER) + 1e-8f), 0.2f);
        R[idx] = (bf16_t)v;
    } else if (b < 132 + 2048) {         // E: 2048*256*8 = 4194304 elems exact
        int idx = (b - 132) * 256 + threadIdx.x;
        const f32x4* s = (const f32x4*)E;
        f32x4 v0 = s[idx * 2], v1 = s[idx * 2 + 1];
        bf16x8 o;
        o[0] = (bf16_t)v0[0]; o[1] = (bf16_t)v0[1]; o[2] = (bf16_t)v0[2]; o[3] = (bf16_t)v0[3];
        o[4] = (bf16_t)v1[0]; o[5] = (bf16_t)v1[1]; o[6] = (bf16_t)v1[2]; o[7] = (bf16_t)v1[3];
        ((bf16x8*)Eb)[idx] = o;
    } else {                             // W: 512*256*8 = 1048576 elems exact
        int idx = (b - 2180) * 256 + threadIdx.x;
        const f32x4* s = (const f32x4*)W;
        f32x4 v0 = s[idx * 2], v1 = s[idx * 2 + 1];
        bf16x8 o;
        o[0] = (bf16_t)v0[0]; o[1] = (bf16_t)v0[1]; o[2] = (bf16_t)v0[2]; o[3] = (bf16_t)v0[3];
        o[4] = (bf16_t)v1[0]; o[5] = (bf16_t)v1[1]; o[6] = (bf16_t)v1[2]; o[7] = (bf16_t)v1[3];
        ((bf16x8*)Wb)[idx] = o;
    }
}

// ---------------------------------------------------------------------------
// Shared lane machinery. LDS (where used) linear [row][64], XOR chunk
// swizzle on BOTH sides (rule 21).
// ---------------------------------------------------------------------------
#define GA_LANES()                                                           \
    const int tid  = threadIdx.x;                                            \
    const int wave = tid >> 6;                                               \
    const int lane = tid & 63;                                               \
    const int quad = lane >> 4;                                              \
    const int ln   = lane & 15;                                              \
    const int wm   = wave >> 1;                                              \
    const int wn   = wave & 1;                                               \
    const int lrow = lane >> 3;                                              \
    const int lch  = (lane & 7) ^ lrow;                                      \
    const int rsw   = ln & 7;                                                \
    const int coff0 = ((quad ^ rsw)) * 8;                                    \
    const int coff1 = (((4 + quad) ^ rsw)) * 8;

// ---------------------------------------------------------------------------
// gemm_a: BM=128, BN=128, BK=64, split-j. 512 blocks (2/CU); pair (bid,bid+256)
// shares a CU -> per-CU work = (I+1) + (32-I) = 33 steps. B (Eb) staged via
// glds16 double-buffer; A (Toeplitz R) read directly from L1/L2 per fragment.
// ---------------------------------------------------------------------------
#define GA_STAGE_B(SBOFS)                                                    \
    _Pragma("unroll")                                                        \
    for (int c = 0; c < 4; ++c) {                                            \
        glds16(pB[c], &sB[(SBOFS) + (c * 32 + wave * 8) * 64]);              \
        pB[c] += 64;                                                         \
    }

// A fragment (row r' = wm*64+tm*16+ln, col kk*32+quad*8+k):
//   R[(ln&7)*R_STRIDE + R_O0-i0+j0 - 64*wm - 8*(ln>>3) - 16*tm + kk*32+quad*8+k]
#define GA_COMPUTE(SBOFS)                                                    \
    _Pragma("unroll")                                                        \
    for (int kk = 0; kk < 2; ++kk) {                                         \
        const int co = kk ? coff1 : coff0;                                   \
        bf16x8 afr[4], bfr[4];                                               \
        _Pragma("unroll")                                                    \
        for (int tm = 0; tm < 4; ++tm)                                       \
            afr[tm] = *(const bf16x8*)(pRA + (kk * 32 + quad * 8 - 16 * tm)); \
        _Pragma("unroll")                                                    \
        for (int tn = 0; tn < 4; ++tn)                                       \
            bfr[tn] = *(const bf16x8*)&sB[(SBOFS) + (wn * 64 + tn * 16 + ln) * 64 + co]; \
        _Pragma("unroll")                                                    \
        for (int tm = 0; tm < 4; ++tm)                                       \
            _Pragma("unroll")                                                \
            for (int tn = 0; tn < 4; ++tn)                                   \
                acc[tm][tn] = __builtin_amdgcn_mfma_f32_16x16x32_bf16(afr[tm], bfr[tn], acc[tm][tn], 0, 0, 0); \
    }                                                                        \
    pRA += 64;

__global__ __launch_bounds__(256, 2) void gemm_a_kernel(const bf16_t* __restrict__ R,
                                                        const bf16_t* __restrict__ Eb,
                                                        bf16_t* __restrict__ T0,
                                                        bf16_t* __restrict__ T1) {
    __shared__ __align__(16) bf16_t sB[2 * 128 * 64];   // 32 KB (B only)

    const int bid = blockIdx.x;
    int I, nb, h;
    if (bid < 256) { I = bid >> 3;                nb = bid & 7;         h = 0; }
    else           { I = 31 - ((bid - 256) >> 3); nb = (bid - 256) & 7; h = 1; }
    const int i0 = I * 128;
    const int n0 = nb * 128;
    const int nsteps = I + 1;
    const int j0b = h ? 64 * (I + 1) : 0;
    bf16_t* __restrict__ Tout = h ? T1 : T0;

    GA_LANES()

    f32x4 acc[4][4];
#pragma unroll
    for (int a = 0; a < 4; ++a)
#pragma unroll
        for (int b = 0; b < 4; ++b) acc[a][b] = (f32x4){0, 0, 0, 0};

    // Direct-A base pointer (per lane): replica ln&7, back-off 64*wm+8*(ln>>3)
    const bf16_t* pRA = R + (size_t)(ln & 7) * R_STRIDE +
                        (R_O0 - i0 + j0b - 64 * wm - 8 * (ln >> 3) + 48);
    // NOTE: +48 compensates the -16*tm term's range so all imm offsets are
    // within [-0,+..]: actual fragment addr uses (kk*32+quad*8-16*tm) with
    // tm in [0,4) -> range [-48,+56]; folding +48 keeps byte offsets >= 0.
    pRA -= 48;  // keep exact original mapping (see GA_COMPUTE formula)

    const bf16_t* pB[4];
#pragma unroll
    for (int c = 0; c < 4; ++c)
        pB[c] = Eb + (size_t)(n0 + c * 32 + wave * 8 + lrow) * L_SER + j0b + lch * 8;

    GA_STAGE_B(0)                                // step 0 -> buf0
    for (int s = 0;; s += 2) {
        __syncthreads();                         // drains buf0 stage
        if (s + 1 < nsteps) { GA_STAGE_B(128 * 64) }
        GA_COMPUTE(0)
        if (s + 1 >= nsteps) break;
        __syncthreads();                         // drains buf1 stage
        if (s + 2 < nsteps) { GA_STAGE_B(0) }
        GA_COMPUTE(128 * 64)
        if (s + 2 >= nsteps) break;
    }

    // C/D: col = ln, row = quad*4 + r (m89-verified)
#pragma unroll
    for (int tm = 0; tm < 4; ++tm) {
        int row_base = i0 + wm * 64 + tm * 16 + quad * 4;
#pragma unroll
        for (int tn = 0; tn < 4; ++tn) {
            int col = n0 + wn * 64 + tn * 16 + ln;
#pragma unroll
            for (int r = 0; r < 4; ++r)
                Tout[(size_t)(row_base + r) * DEMB + col] = (bf16_t)acc[tm][tn][r];
        }
    }
}

// ---------------------------------------------------------------------------
// gemm_b: BM=64, BN=128, BK=64, K=1024, dual A-stream (T0,T1). 512 blocks
// (2/CU). A-LDS rows 0..63 = T0 tile, rows 64..127 = T1 tile (staged via
// glds16, both-sides swizzle); B (W) fragments read directly from L1/L2.
// Per kk: 4 afr LDS reads + 4 bfr global reads, 16 MFMA into acc[2][4].
// ---------------------------------------------------------------------------
#define GB_STAGE_A(SBOFS)                                                    \
    _Pragma("unroll")                                                        \
    for (int c = 0; c < 4; ++c) {                                            \
        glds16(pA[c], &sA[(SBOFS) + (c * 32 + wave * 8) * 64]);              \
        pA[c] += 64;                                                         \
    }

#define GB_COMPUTE(SBOFS)                                                    \
    _Pragma("unroll")                                                        \
    for (int kk = 0; kk < 2; ++kk) {                                         \
        const int co = kk ? coff1 : coff0;                                   \
        bf16x8 afr[4], bfr[4];                                               \
        _Pragma("unroll")                                                    \
        for (int c = 0; c < 4; ++c)                                          \
            afr[c] = *(const bf16x8*)&sA[(SBOFS) + (((c >> 1) * 64) + wm * 32 + (c & 1) * 16 + ln) * 64 + co]; \
        _Pragma("unroll")                                                    \
        for (int tn = 0; tn < 4; ++tn)                                       \
            bfr[tn] = *(const bf16x8*)(pWg[tn] + kk * 32 + quad * 8);        \
        _Pragma("unroll")                                                    \
        for (int t = 0; t < 2; ++t)                                          \
            _Pragma("unroll")                                                \
            for (int tn = 0; tn < 4; ++tn)                                   \
                acc[t][tn] = __builtin_amdgcn_mfma_f32_16x16x32_bf16(afr[t], bfr[tn], acc[t][tn], 0, 0, 0); \
        _Pragma("unroll")                                                    \
        for (int t = 0; t < 2; ++t)                                          \
            _Pragma("unroll")                                                \
            for (int tn = 0; tn < 4; ++tn)                                   \
                acc[t][tn] = __builtin_amdgcn_mfma_f32_16x16x32_bf16(afr[2 + t], bfr[tn], acc[t][tn], 0, 0, 0); \
    }                                                                        \
    _Pragma("unroll")                                                        \
    for (int tn = 0; tn < 4; ++tn) pWg[tn] += 64;

__global__ __launch_bounds__(256, 2) void gemm_b_kernel(const bf16_t* __restrict__ T0,
                                                        const bf16_t* __restrict__ T1,
                                                        const bf16_t* __restrict__ Wb,
                                                        float* __restrict__ out) {
    __shared__ __align__(16) bf16_t sA[2 * 128 * 64];   // 32 KB (A only)

    const int bid = blockIdx.x;
    const int ib = bid >> 3;        // 0..63
    const int nb = bid & 7;
    const int i0 = ib * 64;
    const int n0 = nb * 128;

    GA_LANES()

    f32x4 acc[2][4];
#pragma unroll
    for (int a = 0; a < 2; ++a)
#pragma unroll
        for (int b = 0; b < 4; ++b) acc[a][b] = (f32x4){0, 0, 0, 0};

    const int nsteps = DEMB / 64;   // 16 (even)

    // A staging: c=0,1 -> T0 rows (c&1)*32+..., LDS rows 0..63;
    //            c=2,3 -> T1 rows (c&1)*32+..., LDS rows 64..127.
    const bf16_t* pA[4];
#pragma unroll
    for (int c = 0; c < 4; ++c) {
        const bf16_t* base = (c < 2) ? T0 : T1;
        int rr = (c & 1) * 32 + wave * 8 + lrow;
        pA[c] = base + (size_t)(i0 + rr) * DEMB + lch * 8;
    }
    // Direct-B row pointers: row = n0 + wn*64 + tn*16 + ln
    const bf16_t* pWg[4];
#pragma unroll
    for (int tn = 0; tn < 4; ++tn)
        pWg[tn] = Wb + (size_t)(n0 + wn * 64 + tn * 16 + ln) * DEMB;

    GB_STAGE_A(0)                                // step 0 -> buf0
    for (int s = 0;; s += 2) {
        __syncthreads();                         // drains buf0 stage
        if (s + 1 < nsteps) { GB_STAGE_A(128 * 64) }
        GB_COMPUTE(0)
        if (s + 1 >= nsteps) break;
        __syncthreads();                         // drains buf1 stage
        if (s + 2 < nsteps) { GB_STAGE_A(0) }
        GB_COMPUTE(128 * 64)
        if (s + 2 >= nsteps) break;
    }

#pragma unroll
    for (int t = 0; t < 2; ++t) {
        int row_base = i0 + wm * 32 + t * 16 + quad * 4;
#pragma unroll
        for (int tn = 0; tn < 4; ++tn) {
            int col = n0 + wn * 64 + tn * 16 + ln;
#pragma unroll
            for (int r = 0; r < 4; ++r)
                out[(size_t)(row_base + r) * DV + col] = acc[t][tn][r];
        }
    }
}

// ---------------------------------------------------------------------------
extern "C" void kernel_launch(void* const* d_in, const int* in_sizes, int n_in,
                              void* d_out, int out_size, void* d_ws, size_t ws_size,
                              hipStream_t stream) {
    const float* E = (const float*)d_in[0];   // (1024, 4096) f32
    const float* W = (const float*)d_in[1];   // (1024, 1024) f32
    float* out = (float*)d_out;               // (4096, 1024) f32

    char* ws = (char*)d_ws;
    bf16_t* Eb = (bf16_t*)(ws);                               // 8 MB
    bf16_t* T0 = (bf16_t*)(ws + (size_t)8  * 1024 * 1024);    // 8 MB
    bf16_t* T1 = (bf16_t*)(ws + (size_t)16 * 1024 * 1024);    // 8 MB
    bf16_t* Wb = (bf16_t*)(ws + (size_t)24 * 1024 * 1024);    // 2 MB
    bf16_t* R  = (bf16_t*)(ws + (size_t)26 * 1024 * 1024);    // 66 KB

    prep_kernel<<<2692, 256, 0, stream>>>(E, W, Eb, Wb, R);
    gemm_a_kernel<<<512, 256, 0, stream>>>(R, Eb, T0, T1);
    gemm_b_kernel<<<512, 256, 0, stream>>>(T0, T1, Wb, out);
}

// Round 10
// 123.319 us; speedup vs baseline: 1.1901x; 1.1901x over previous
//
#include <hip/hip_runtime.h>
#include <hip/hip_bf16.h>
#include <cstdint>
#include <cstddef>

// out = (A2 @ E^T) @ W^T, A2[i,j] = a[i-j] lower-tri Toeplitz,
//   a[d] = (d/4096 + 1e-8)^0.2, a[0] = 1e-8^0.2
// gemm_a: T[i,e] = sum_{j<=i} a[i-j] * E[e,j]  (tri, split-j -> T0 + T1)
// gemm_b: out[i,v] = sum_e T0[i,e]*W[v,e] + sum_e T1[i,e]*W[v,e]
// Round 16: R9 post-mortem: direct global fragment feeds are a gather (L1
// line-limited, latency on the MFMA path) -> reverted; operands must transit
// LDS. New: gemm_a stages the COMPRESSED Toeplitz window (8 rows x 200
// elems, 3.2 KB) instead of the expanded 16 KB A-tile:
//   win[s][y] = R[s][off0-120+y],  A[r'][c] = win[r'&7][120 + c - 8*(r'>>3)]
// 400B row stride -> replica rows 16B-phase-offset in banks -> conflict-free
// b128 fragment reads; staged via ONE lane-linear glds16 per thread
// (slot=tid: row=tid/25, chunk=tid%25; slots>=200 fill a junk quarter of the
// 4KB buffer, values unused; R padded +512 elems so all reads initialized).
// gemm_a staged bytes/step 32->19.2 KB, A VMEM ops/thread 4->1, LDS 64->40KB.
// gemm_b: byte-identical to R8's verified dual-A-stream kernel.

#define L_SER 4096
#define DEMB  1024
#define DV    1024

#define R_STRIDE 4224   // shift-replica stride of reversed a; 16B-aligned
#define R_O0     4096

typedef __bf16 bf16_t;
typedef __attribute__((ext_vector_type(8))) __bf16 bf16x8;
typedef __attribute__((ext_vector_type(4))) float f32x4;

// direct global->LDS async copy, 16B per lane (dest = uniform base + lane*16)
__device__ __forceinline__ void glds16(const bf16_t* g, bf16_t* l) {
    __builtin_amdgcn_global_load_lds(
        (const __attribute__((address_space(1))) unsigned int*)(const void*)g,
        (__attribute__((address_space(3))) unsigned int*)(void*)l,
        16, 0, 0);
}

// ---------------------------------------------------------------------------
// Fused prep: blocks [0,134) build R (+pad); [134,2182) convert E;
// [2182,2694) convert W.
// ---------------------------------------------------------------------------
__global__ void prep_kernel(const float* __restrict__ E, const float* __restrict__ W,
                            bf16_t* __restrict__ Eb, bf16_t* __restrict__ Wb,
                            bf16_t* __restrict__ R) {
    const int b = blockIdx.x;
    if (b < 134) {                       // 134*256 = 34304 = 8*4224 + 512 pad
        int idx = b * 256 + threadIdx.x;
        int s = idx / R_STRIDE;
        int x = idx - s * R_STRIDE;
        int d = R_O0 + s - x;
        float v = 0.0f;
        if (d >= 0 && d < L_SER)
            v = powf((d == 0) ? 1e-8f : ((float)d * (1.0f / (float)L_SER) + 1e-8f), 0.2f);
        R[idx] = (bf16_t)v;
    } else if (b < 134 + 2048) {         // E: 2048*256*8 = 4194304 elems exact
        int idx = (b - 134) * 256 + threadIdx.x;
        const f32x4* s = (const f32x4*)E;
        f32x4 v0 = s[idx * 2], v1 = s[idx * 2 + 1];
        bf16x8 o;
        o[0] = (bf16_t)v0[0]; o[1] = (bf16_t)v0[1]; o[2] = (bf16_t)v0[2]; o[3] = (bf16_t)v0[3];
        o[4] = (bf16_t)v1[0]; o[5] = (bf16_t)v1[1]; o[6] = (bf16_t)v1[2]; o[7] = (bf16_t)v1[3];
        ((bf16x8*)Eb)[idx] = o;
    } else {                             // W: 512*256*8 = 1048576 elems exact
        int idx = (b - 2182) * 256 + threadIdx.x;
        const f32x4* s = (const f32x4*)W;
        f32x4 v0 = s[idx * 2], v1 = s[idx * 2 + 1];
        bf16x8 o;
        o[0] = (bf16_t)v0[0]; o[1] = (bf16_t)v0[1]; o[2] = (bf16_t)v0[2]; o[3] = (bf16_t)v0[3];
        o[4] = (bf16_t)v1[0]; o[5] = (bf16_t)v1[1]; o[6] = (bf16_t)v1[2]; o[7] = (bf16_t)v1[3];
        ((bf16x8*)Wb)[idx] = o;
    }
}

// ---------------------------------------------------------------------------
// Shared lane machinery. LDS (expanded tiles) linear [row][64], XOR chunk
// swizzle on BOTH sides (rule 21). Window buffer: [8][200] elems, 400B rows.
// ---------------------------------------------------------------------------
#define GA_LANES()                                                           \
    const int tid  = threadIdx.x;                                            \
    const int wave = tid >> 6;                                               \
    const int lane = tid & 63;                                               \
    const int quad = lane >> 4;                                              \
    const int ln   = lane & 15;                                              \
    const int wm   = wave >> 1;                                              \
    const int wn   = wave & 1;                                               \
    const int lrow = lane >> 3;                                              \
    const int lch  = (lane & 7) ^ lrow;                                      \
    const int rsw   = ln & 7;                                                \
    const int coff0 = ((quad ^ rsw)) * 8;                                    \
    const int coff1 = (((4 + quad) ^ rsw)) * 8;

// ---------------------------------------------------------------------------
// gemm_a: BM=128, BN=128, BK=64, split-j. 512 blocks (2/CU); pair (bid,bid+256)
// shares a CU -> per-CU work = (I+1) + (32-I) = 33 steps.
// B (Eb) staged expanded (4 glds16/thread); A staged as compressed window
// (1 glds16/thread into [8][200], buffers at 0/2048 elems).
// ---------------------------------------------------------------------------
#define GA_STAGE(SBOFS, WOFS)                                                \
    _Pragma("unroll")                                                        \
    for (int c = 0; c < 4; ++c) {                                            \
        glds16(pB[c], &sB[(SBOFS) + (c * 32 + wave * 8) * 64]);              \
        pB[c] += 64;                                                         \
    }                                                                        \
    glds16(pRwin, &sW[(WOFS) + wave * 512]);                                 \
    pRwin += 64;

// A fragment (row r' = wm*64+tm*16+ln, col c = kk*32+quad*8+j):
//   win[ln&7][120 + c - 8*(wm*8 + tm*2 + (ln>>3))]
#define GA_COMPUTE(SBOFS, WOFS)                                              \
    _Pragma("unroll")                                                        \
    for (int kk = 0; kk < 2; ++kk) {                                         \
        const int co = kk ? coff1 : coff0;                                   \
        bf16x8 afr[4], bfr[4];                                               \
        _Pragma("unroll")                                                    \
        for (int tm = 0; tm < 4; ++tm)                                       \
            afr[tm] = *(const bf16x8*)&sW[(WOFS) + awbase + (kk * 32 + quad * 8 - 16 * tm)]; \
        _Pragma("unroll")                                                    \
        for (int tn = 0; tn < 4; ++tn)                                       \
            bfr[tn] = *(const bf16x8*)&sB[(SBOFS) + (wn * 64 + tn * 16 + ln) * 64 + co]; \
        _Pragma("unroll")                                                    \
        for (int tm = 0; tm < 4; ++tm)                                       \
            _Pragma("unroll")                                                \
            for (int tn = 0; tn < 4; ++tn)                                   \
                acc[tm][tn] = __builtin_amdgcn_mfma_f32_16x16x32_bf16(afr[tm], bfr[tn], acc[tm][tn], 0, 0, 0); \
    }

__global__ __launch_bounds__(256, 2) void gemm_a_kernel(const bf16_t* __restrict__ R,
                                                        const bf16_t* __restrict__ Eb,
                                                        bf16_t* __restrict__ T0,
                                                        bf16_t* __restrict__ T1) {
    __shared__ __align__(16) bf16_t sB[2 * 128 * 64];   // 32 KB (B tiles)
    __shared__ __align__(16) bf16_t sW[2 * 2048];       // 8 KB (A windows; [8][200]+junk)

    const int bid = blockIdx.x;
    int I, nb, h;
    if (bid < 256) { I = bid >> 3;                nb = bid & 7;         h = 0; }
    else           { I = 31 - ((bid - 256) >> 3); nb = (bid - 256) & 7; h = 1; }
    const int i0 = I * 128;
    const int n0 = nb * 128;
    const int nsteps = I + 1;
    const int j0b = h ? 64 * (I + 1) : 0;
    bf16_t* __restrict__ Tout = h ? T1 : T0;

    GA_LANES()

    // window fragment-read base (elems): row (ln&7), y = 120 - 64*wm - 8*(ln>>3)
    const int awbase = (ln & 7) * 200 + 120 - 64 * wm - 8 * (ln >> 3);

    f32x4 acc[4][4];
#pragma unroll
    for (int a = 0; a < 4; ++a)
#pragma unroll
        for (int b = 0; b < 4; ++b) acc[a][b] = (f32x4){0, 0, 0, 0};

    // Window staging source: slot = tid, row = slot/25, chunk = slot%25;
    // src = R[row][off0 - 120 + chunk*8], off0 = R_O0 - i0 + j0b (advances 64/step).
    // Rows 8..10 / slots >= 200 read initialized pad (values unused).
    const int wrow = tid / 25;
    const int wchk = tid - wrow * 25;
    const bf16_t* pRwin = R + (size_t)wrow * R_STRIDE + (R_O0 - i0 + j0b - 120 + wchk * 8);

    const bf16_t* pB[4];
#pragma unroll
    for (int c = 0; c < 4; ++c)
        pB[c] = Eb + (size_t)(n0 + c * 32 + wave * 8 + lrow) * L_SER + j0b + lch * 8;

    GA_STAGE(0, 0)                               // step 0 -> buf0
    for (int s = 0;; s += 2) {
        __syncthreads();                         // drains buf0 stage
        if (s + 1 < nsteps) { GA_STAGE(128 * 64, 2048) }
        GA_COMPUTE(0, 0)
        if (s + 1 >= nsteps) break;
        __syncthreads();                         // drains buf1 stage
        if (s + 2 < nsteps) { GA_STAGE(0, 0) }
        GA_COMPUTE(128 * 64, 2048)
        if (s + 2 >= nsteps) break;
    }

    // C/D: col = ln, row = quad*4 + r (m89-verified)
#pragma unroll
    for (int tm = 0; tm < 4; ++tm) {
        int row_base = i0 + wm * 64 + tm * 16 + quad * 4;
#pragma unroll
        for (int tn = 0; tn < 4; ++tn) {
            int col = n0 + wn * 64 + tn * 16 + ln;
#pragma unroll
            for (int r = 0; r < 4; ++r)
                Tout[(size_t)(row_base + r) * DEMB + col] = (bf16_t)acc[tm][tn][r];
        }
    }
}

// ---------------------------------------------------------------------------
// gemm_b: BM=64, BN=128, BK=64, K=1024, dual A-stream (T0,T1). 512 blocks
// (2/CU). A-LDS rows 0..63 = T0 tile, rows 64..127 = T1 tile; per kk: 4 afr
// + 4 bfr reads, 16 MFMA (8 per stream) into acc[2][4]. (R8-verified.)
// ---------------------------------------------------------------------------
#define GB_STAGE(SBOFS)                                                      \
    _Pragma("unroll")                                                        \
    for (int c = 0; c < 4; ++c) {                                            \
        glds16(pA[c], &sA[(SBOFS) + (c * 32 + wave * 8) * 64]);              \
        glds16(pW[c], &sBB[(SBOFS) + (c * 32 + wave * 8) * 64]);             \
        pA[c] += 64; pW[c] += 64;                                            \
    }

#define GB_COMPUTE(SBOFS)                                                    \
    _Pragma("unroll")                                                        \
    for (int kk = 0; kk < 2; ++kk) {                                         \
        const int co = kk ? coff1 : coff0;                                   \
        bf16x8 afr[4], bfr[4];                                               \
        _Pragma("unroll")                                                    \
        for (int c = 0; c < 4; ++c)                                          \
            afr[c] = *(const bf16x8*)&sA[(SBOFS) + (((c >> 1) * 64) + wm * 32 + (c & 1) * 16 + ln) * 64 + co]; \
        _Pragma("unroll")                                                    \
        for (int tn = 0; tn < 4; ++tn)                                       \
            bfr[tn] = *(const bf16x8*)&sBB[(SBOFS) + (wn * 64 + tn * 16 + ln) * 64 + co]; \
        _Pragma("unroll")                                                    \
        for (int t = 0; t < 2; ++t)                                          \
            _Pragma("unroll")                                                \
            for (int tn = 0; tn < 4; ++tn)                                   \
                acc[t][tn] = __builtin_amdgcn_mfma_f32_16x16x32_bf16(afr[t], bfr[tn], acc[t][tn], 0, 0, 0); \
        _Pragma("unroll")                                                    \
        for (int t = 0; t < 2; ++t)                                          \
            _Pragma("unroll")                                                \
            for (int tn = 0; tn < 4; ++tn)                                   \
                acc[t][tn] = __builtin_amdgcn_mfma_f32_16x16x32_bf16(afr[2 + t], bfr[tn], acc[t][tn], 0, 0, 0); \
    }

__global__ __launch_bounds__(256, 2) void gemm_b_kernel(const bf16_t* __restrict__ T0,
                                                        const bf16_t* __restrict__ T1,
                                                        const bf16_t* __restrict__ Wb,
                                                        float* __restrict__ out) {
    __shared__ __align__(16) bf16_t sA[2 * 128 * 64];    // 32 KB
    __shared__ __align__(16) bf16_t sBB[2 * 128 * 64];   // 32 KB

    const int bid = blockIdx.x;
    const int ib = bid >> 3;        // 0..63
    const int nb = bid & 7;
    const int i0 = ib * 64;
    const int n0 = nb * 128;

    GA_LANES()

    f32x4 acc[2][4];
#pragma unroll
    for (int a = 0; a < 2; ++a)
#pragma unroll
        for (int b = 0; b < 4; ++b) acc[a][b] = (f32x4){0, 0, 0, 0};

    const int nsteps = DEMB / 64;   // 16 (even)

    // A staging: c=0,1 -> T0 rows (c&1)*32+..., LDS rows 0..63;
    //            c=2,3 -> T1 rows (c&1)*32+..., LDS rows 64..127.
    const bf16_t* pA[4];
    const bf16_t* pW[4];
#pragma unroll
    for (int c = 0; c < 4; ++c) {
        const bf16_t* base = (c < 2) ? T0 : T1;
        int rr = (c & 1) * 32 + wave * 8 + lrow;
        pA[c] = base + (size_t)(i0 + rr) * DEMB + lch * 8;
        pW[c] = Wb + (size_t)(n0 + c * 32 + wave * 8 + lrow) * DEMB + lch * 8;
    }

    GB_STAGE(0)                                  // step 0 -> buf0
    for (int s = 0;; s += 2) {
        __syncthreads();                         // drains buf0 stage
        if (s + 1 < nsteps) { GB_STAGE(128 * 64) }
        GB_COMPUTE(0)
        if (s + 1 >= nsteps) break;
        __syncthreads();                         // drains buf1 stage
        if (s + 2 < nsteps) { GB_STAGE(0) }
        GB_COMPUTE(128 * 64)
        if (s + 2 >= nsteps) break;
    }

#pragma unroll
    for (int t = 0; t < 2; ++t) {
        int row_base = i0 + wm * 32 + t * 16 + quad * 4;
#pragma unroll
        for (int tn = 0; tn < 4; ++tn) {
            int col = n0 + wn * 64 + tn * 16 + ln;
#pragma unroll
            for (int r = 0; r < 4; ++r)
                out[(size_t)(row_base + r) * DV + col] = acc[t][tn][r];
        }
    }
}

// ---------------------------------------------------------------------------
extern "C" void kernel_launch(void* const* d_in, const int* in_sizes, int n_in,
                              void* d_out, int out_size, void* d_ws, size_t ws_size,
                              hipStream_t stream) {
    const float* E = (const float*)d_in[0];   // (1024, 4096) f32
    const float* W = (const float*)d_in[1];   // (1024, 1024) f32
    float* out = (float*)d_out;               // (4096, 1024) f32

    char* ws = (char*)d_ws;
    bf16_t* Eb = (bf16_t*)(ws);                               // 8 MB
    bf16_t* T0 = (bf16_t*)(ws + (size_t)8  * 1024 * 1024);    // 8 MB
    bf16_t* T1 = (bf16_t*)(ws + (size_t)16 * 1024 * 1024);    // 8 MB
    bf16_t* Wb = (bf16_t*)(ws + (size_t)24 * 1024 * 1024);    // 2 MB
    bf16_t* R  = (bf16_t*)(ws + (size_t)26 * 1024 * 1024);    // 67 KB (+pad)

    prep_kernel<<<2694, 256, 0, stream>>>(E, W, Eb, Wb, R);
    gemm_a_kernel<<<512, 256, 0, stream>>>(R, Eb, T0, T1);
    gemm_b_kernel<<<512, 256, 0, stream>>>(T0, T1, Wb, out);
}

// Round 12
// 117.493 us; speedup vs baseline: 1.2491x; 1.0496x over previous
//
#include <hip/hip_runtime.h>
#include <hip/hip_bf16.h>
#include <cstdint>
#include <cstddef>

// out = (A2 @ E^T) @ W^T, A2[i,j] = a[i-j] lower-tri Toeplitz,
//   a[d] = (d/4096 + 1e-8)^0.2, a[0] = 1e-8^0.2
// gemm_a: T[i,e] = sum_{j<=i} a[i-j] * E[e,j]  (tri, split-j -> T0 + T1)
// gemm_b: out[i,v] = sum_e T0[i,e]*W[v,e] + sum_e T1[i,e]*W[v,e]
// Round 18: R11's BK=128 failed from DOUBLE COUNTING: for even I, h=0's
// rounded-up step count covered chunk I+1 while h=1 also started there.
// Fix: h=1 starts at c0 = (I+2)&~1 (one past h=0's coverage), dsteps =
// (2(I+1)-c0)/2; I=0,h=1 has 0 dsteps -> guarded (epilogue still writes the
// zero acc so T1 is defined). Padded chunk (even I, h=0) legally reads
// stored zeros above the diagonal from R (R_STRIDE 4352, zero tail).
// Everything else identical to R11 (= verified R10 outside gemm_a):
// B-LDS [2][128][128], swizzle slot=(kk*4+quad)^(row&7); A = compressed
// window [2][8][248]; gemm_b = R8/R10-verified dual-A-stream kernel.

#define L_SER 4096
#define DEMB  1024
#define DV    1024

#define R_STRIDE 4352   // shift-replica stride of reversed a; 16B-aligned; zero-padded tail
#define R_O0     4096

typedef __bf16 bf16_t;
typedef __attribute__((ext_vector_type(8))) __bf16 bf16x8;
typedef __attribute__((ext_vector_type(4))) float f32x4;

// direct global->LDS async copy, 16B per lane (dest = uniform base + lane*16)
__device__ __forceinline__ void glds16(const bf16_t* g, bf16_t* l) {
    __builtin_amdgcn_global_load_lds(
        (const __attribute__((address_space(1))) unsigned int*)(const void*)g,
        (__attribute__((address_space(3))) unsigned int*)(void*)l,
        16, 0, 0);
}

// ---------------------------------------------------------------------------
// Fused prep: blocks [0,136) build R (8 replicas x 4352, zeros where d
// outside [0,4096)); [136,2184) convert E; [2184,2696) convert W.
// ---------------------------------------------------------------------------
__global__ void prep_kernel(const float* __restrict__ E, const float* __restrict__ W,
                            bf16_t* __restrict__ Eb, bf16_t* __restrict__ Wb,
                            bf16_t* __restrict__ R) {
    const int b = blockIdx.x;
    if (b < 136) {                       // 136*256 = 34816 = 8*4352 exact
        int idx = b * 256 + threadIdx.x;
        int s = idx / R_STRIDE;
        int x = idx - s * R_STRIDE;
        int d = R_O0 + s - x;
        float v = 0.0f;
        if (d >= 0 && d < L_SER)
            v = powf((d == 0) ? 1e-8f : ((float)d * (1.0f / (float)L_SER) + 1e-8f), 0.2f);
        R[idx] = (bf16_t)v;
    } else if (b < 136 + 2048) {         // E: 2048*256*8 = 4194304 elems exact
        int idx = (b - 136) * 256 + threadIdx.x;
        const f32x4* s = (const f32x4*)E;
        f32x4 v0 = s[idx * 2], v1 = s[idx * 2 + 1];
        bf16x8 o;
        o[0] = (bf16_t)v0[0]; o[1] = (bf16_t)v0[1]; o[2] = (bf16_t)v0[2]; o[3] = (bf16_t)v0[3];
        o[4] = (bf16_t)v1[0]; o[5] = (bf16_t)v1[1]; o[6] = (bf16_t)v1[2]; o[7] = (bf16_t)v1[3];
        ((bf16x8*)Eb)[idx] = o;
    } else {                             // W: 512*256*8 = 1048576 elems exact
        int idx = (b - 2184) * 256 + threadIdx.x;
        const f32x4* s = (const f32x4*)W;
        f32x4 v0 = s[idx * 2], v1 = s[idx * 2 + 1];
        bf16x8 o;
        o[0] = (bf16_t)v0[0]; o[1] = (bf16_t)v0[1]; o[2] = (bf16_t)v0[2]; o[3] = (bf16_t)v0[3];
        o[4] = (bf16_t)v1[0]; o[5] = (bf16_t)v1[1]; o[6] = (bf16_t)v1[2]; o[7] = (bf16_t)v1[3];
        ((bf16x8*)Wb)[idx] = o;
    }
}

// ---------------------------------------------------------------------------
// Shared lane machinery.
// ---------------------------------------------------------------------------
#define GA_LANES()                                                           \
    const int tid  = threadIdx.x;                                            \
    const int wave = tid >> 6;                                               \
    const int lane = tid & 63;                                               \
    const int quad = lane >> 4;                                              \
    const int ln   = lane & 15;                                              \
    const int wm   = wave >> 1;                                              \
    const int wn   = wave & 1;                                               \
    const int lrow = lane >> 3;                                              \
    const int lch  = (lane & 7) ^ lrow;                                      \
    const int rsw   = ln & 7;                                                \
    const int coff0 = ((quad ^ rsw)) * 8;                                    \
    const int coff1 = (((4 + quad) ^ rsw)) * 8;

// ---------------------------------------------------------------------------
// gemm_a: BM=128, BN=128, BK=128. 512 blocks (2/CU); pair (bid,bid+256)
// shares a CU -> 16-17 double-steps per CU. B-LDS [2][128][128] (64 KB),
// swizzle slot=(kk*4+quad)^(row&7); A = compressed window [2][8][248] (8 KB).
// ---------------------------------------------------------------------------
#define GA2_STAGE(SBOFS, WOFS)                                               \
    _Pragma("unroll")                                                        \
    for (int c = 0; c < 8; ++c) {                                            \
        glds16(pB[c], &sB[(SBOFS) + (c * 16 + wave * 4) * 128]);             \
        pB[c] += 128;                                                        \
    }                                                                        \
    glds16(pRwin, &sW[(WOFS) + wave * 512]);                                 \
    pRwin += 128;

// A fragment (row r' = wm*64+tm*16+ln, col c = kk*32+quad*8+j):
//   win[ln&7][120 + c - 8*(wm*8 + tm*2 + (ln>>3))]
#define GA2_COMPUTE(SBOFS, WOFS)                                             \
    _Pragma("unroll")                                                        \
    for (int kk = 0; kk < 4; ++kk) {                                         \
        const int co = (((kk * 4 + quad) ^ rsw)) * 8;                        \
        bf16x8 afr[4], bfr[4];                                               \
        _Pragma("unroll")                                                    \
        for (int tm = 0; tm < 4; ++tm)                                       \
            afr[tm] = *(const bf16x8*)&sW[(WOFS) + awbase + (kk * 32 + quad * 8 - 16 * tm)]; \
        _Pragma("unroll")                                                    \
        for (int tn = 0; tn < 4; ++tn)                                       \
            bfr[tn] = *(const bf16x8*)&sB[(SBOFS) + (wn * 64 + tn * 16 + ln) * 128 + co]; \
        _Pragma("unroll")                                                    \
        for (int tm = 0; tm < 4; ++tm)                                       \
            _Pragma("unroll")                                                \
            for (int tn = 0; tn < 4; ++tn)                                   \
                acc[tm][tn] = __builtin_amdgcn_mfma_f32_16x16x32_bf16(afr[tm], bfr[tn], acc[tm][tn], 0, 0, 0); \
    }

__global__ __launch_bounds__(256, 2) void gemm_a_kernel(const bf16_t* __restrict__ R,
                                                        const bf16_t* __restrict__ Eb,
                                                        bf16_t* __restrict__ T0,
                                                        bf16_t* __restrict__ T1) {
    __shared__ __align__(16) bf16_t sB[2 * 128 * 128];  // 64 KB (B tiles)
    __shared__ __align__(16) bf16_t sW[2 * 2048];       // 8 KB (A windows [8][248]+junk)

    const int bid = blockIdx.x;
    int I, nb, h;
    if (bid < 256) { I = bid >> 3;                nb = bid & 7;         h = 0; }
    else           { I = 31 - ((bid - 256) >> 3); nb = (bid - 256) & 7; h = 1; }
    const int i0 = I * 128;
    const int n0 = nb * 128;
    // split-j in 64-chunks: total = 2(I+1). h=0 covers [0, 2*ceil((I+1)/2))
    // (may include one padded chunk: zeros above diagonal come from R).
    // h=1 covers [c0, 2(I+1)) with c0 = (I+2)&~1 -- NO overlap (R11 fix).
    const int c0 = h ? ((I + 2) & ~1) : 0;
    const int nsteps2 = h ? ((2 * (I + 1) - c0) >> 1) : ((I + 2) >> 1);
    const int j0b = c0 * 64;
    bf16_t* __restrict__ Tout = h ? T1 : T0;

    GA_LANES()

    // window fragment-read base (elems): row (ln&7), y = 120 - 64*wm - 8*(ln>>3)
    const int awbase = (ln & 7) * 248 + 120 - 64 * wm - 8 * (ln >> 3);

    f32x4 acc[4][4];
#pragma unroll
    for (int a = 0; a < 4; ++a)
#pragma unroll
        for (int b = 0; b < 4; ++b) acc[a][b] = (f32x4){0, 0, 0, 0};

    if (nsteps2 > 0) {
        // Window staging: slot = tid (row = slot/31, chunk = slot%31), 248
        // live slots; tids >= 248 duplicate a safe slot (values unused).
        int wrow = tid / 31;
        int wchk = tid - wrow * 31;
        if (tid >= 248) { wrow = 7; wchk = 30; }
        const bf16_t* pRwin = R + (size_t)wrow * R_STRIDE + (R_O0 - i0 + j0b - 120 + wchk * 8);

        // B staging: 8 calls x 4 rows; row = c*16 + wave*4 + (lane>>4),
        // source chunk = (lane&15) ^ ((wave&1)*4 + (lane>>4))
        const int r4  = lane >> 4;
        const int sch = (lane & 15) ^ (((wave & 1) * 4 + r4) & 7);
        const bf16_t* pB[8];
#pragma unroll
        for (int c = 0; c < 8; ++c)
            pB[c] = Eb + (size_t)(n0 + c * 16 + wave * 4 + r4) * L_SER + j0b + sch * 8;

        GA2_STAGE(0, 0)                              // step 0 -> buf0
        for (int s = 0;; s += 2) {
            __syncthreads();                         // drains buf0 stage
            if (s + 1 < nsteps2) { GA2_STAGE(128 * 128, 2048) }
            GA2_COMPUTE(0, 0)
            if (s + 1 >= nsteps2) break;
            __syncthreads();                         // drains buf1 stage
            if (s + 2 < nsteps2) { GA2_STAGE(0, 0) }
            GA2_COMPUTE(128 * 128, 2048)
            if (s + 2 >= nsteps2) break;
        }
    }

    // C/D: col = ln, row = quad*4 + r (m89-verified). Written even when
    // nsteps2==0 (I=0,h=1): zero acc -> defined T1.
#pragma unroll
    for (int tm = 0; tm < 4; ++tm) {
        int row_base = i0 + wm * 64 + tm * 16 + quad * 4;
#pragma unroll
        for (int tn = 0; tn < 4; ++tn) {
            int col = n0 + wn * 64 + tn * 16 + ln;
#pragma unroll
            for (int r = 0; r < 4; ++r)
                Tout[(size_t)(row_base + r) * DEMB + col] = (bf16_t)acc[tm][tn][r];
        }
    }
}

// ---------------------------------------------------------------------------
// gemm_b: BM=64, BN=128, BK=64, K=1024, dual A-stream (T0,T1). 512 blocks
// (2/CU). A-LDS rows 0..63 = T0 tile, rows 64..127 = T1 tile; per kk: 4 afr
// + 4 bfr reads, 16 MFMA (8 per stream) into acc[2][4]. (R8/R10-verified.)
// ---------------------------------------------------------------------------
#define GB_STAGE(SBOFS)                                                      \
    _Pragma("unroll")                                                        \
    for (int c = 0; c < 4; ++c) {                                            \
        glds16(pA[c], &sA[(SBOFS) + (c * 32 + wave * 8) * 64]);              \
        glds16(pW[c], &sBB[(SBOFS) + (c * 32 + wave * 8) * 64]);             \
        pA[c] += 64; pW[c] += 64;                                            \
    }

#define GB_COMPUTE(SBOFS)                                                    \
    _Pragma("unroll")                                                        \
    for (int kk = 0; kk < 2; ++kk) {                                         \
        const int co = kk ? coff1 : coff0;                                   \
        bf16x8 afr[4], bfr[4];                                               \
        _Pragma("unroll")                                                    \
        for (int c = 0; c < 4; ++c)                                          \
            afr[c] = *(const bf16x8*)&sA[(SBOFS) + (((c >> 1) * 64) + wm * 32 + (c & 1) * 16 + ln) * 64 + co]; \
        _Pragma("unroll")                                                    \
        for (int tn = 0; tn < 4; ++tn)                                       \
            bfr[tn] = *(const bf16x8*)&sBB[(SBOFS) + (wn * 64 + tn * 16 + ln) * 64 + co]; \
        _Pragma("unroll")                                                    \
        for (int t = 0; t < 2; ++t)                                          \
            _Pragma("unroll")                                                \
            for (int tn = 0; tn < 4; ++tn)                                   \
                acc[t][tn] = __builtin_amdgcn_mfma_f32_16x16x32_bf16(afr[t], bfr[tn], acc[t][tn], 0, 0, 0); \
        _Pragma("unroll")                                                    \
        for (int t = 0; t < 2; ++t)                                          \
            _Pragma("unroll")                                                \
            for (int tn = 0; tn < 4; ++tn)                                   \
                acc[t][tn] = __builtin_amdgcn_mfma_f32_16x16x32_bf16(afr[2 + t], bfr[tn], acc[t][tn], 0, 0, 0); \
    }

__global__ __launch_bounds__(256, 2) void gemm_b_kernel(const bf16_t* __restrict__ T0,
                                                        const bf16_t* __restrict__ T1,
                                                        const bf16_t* __restrict__ Wb,
                                                        float* __restrict__ out) {
    __shared__ __align__(16) bf16_t sA[2 * 128 * 64];    // 32 KB
    __shared__ __align__(16) bf16_t sBB[2 * 128 * 64];   // 32 KB

    const int bid = blockIdx.x;
    const int ib = bid >> 3;        // 0..63
    const int nb = bid & 7;
    const int i0 = ib * 64;
    const int n0 = nb * 128;

    GA_LANES()

    f32x4 acc[2][4];
#pragma unroll
    for (int a = 0; a < 2; ++a)
#pragma unroll
        for (int b = 0; b < 4; ++b) acc[a][b] = (f32x4){0, 0, 0, 0};

    const int nsteps = DEMB / 64;   // 16 (even)

    // A staging: c=0,1 -> T0 rows (c&1)*32+..., LDS rows 0..63;
    //            c=2,3 -> T1 rows (c&1)*32+..., LDS rows 64..127.
    const bf16_t* pA[4];
    const bf16_t* pW[4];
#pragma unroll
    for (int c = 0; c < 4; ++c) {
        const bf16_t* base = (c < 2) ? T0 : T1;
        int rr = (c & 1) * 32 + wave * 8 + lrow;
        pA[c] = base + (size_t)(i0 + rr) * DEMB + lch * 8;
        pW[c] = Wb + (size_t)(n0 + c * 32 + wave * 8 + lrow) * DEMB + lch * 8;
    }

    GB_STAGE(0)                                  // step 0 -> buf0
    for (int s = 0;; s += 2) {
        __syncthreads();                         // drains buf0 stage
        if (s + 1 < nsteps) { GB_STAGE(128 * 64) }
        GB_COMPUTE(0)
        if (s + 1 >= nsteps) break;
        __syncthreads();                         // drains buf1 stage
        if (s + 2 < nsteps) { GB_STAGE(0) }
        GB_COMPUTE(128 * 64)
        if (s + 2 >= nsteps) break;
    }

#pragma unroll
    for (int t = 0; t < 2; ++t) {
        int row_base = i0 + wm * 32 + t * 16 + quad * 4;
#pragma unroll
        for (int tn = 0; tn < 4; ++tn) {
            int col = n0 + wn * 64 + tn * 16 + ln;
#pragma unroll
            for (int r = 0; r < 4; ++r)
                out[(size_t)(row_base + r) * DV + col] = acc[t][tn][r];
        }
    }
}

// ---------------------------------------------------------------------------
extern "C" void kernel_launch(void* const* d_in, const int* in_sizes, int n_in,
                              void* d_out, int out_size, void* d_ws, size_t ws_size,
                              hipStream_t stream) {
    const float* E = (const float*)d_in[0];   // (1024, 4096) f32
    const float* W = (const float*)d_in[1];   // (1024, 1024) f32
    float* out = (float*)d_out;               // (4096, 1024) f32

    char* ws = (char*)d_ws;
    bf16_t* Eb = (bf16_t*)(ws);                               // 8 MB
    bf16_t* T0 = (bf16_t*)(ws + (size_t)8  * 1024 * 1024);    // 8 MB
    bf16_t* T1 = (bf16_t*)(ws + (size_t)16 * 1024 * 1024);    // 8 MB
    bf16_t* Wb = (bf16_t*)(ws + (size_t)24 * 1024 * 1024);    // 2 MB
    bf16_t* R  = (bf16_t*)(ws + (size_t)26 * 1024 * 1024);    // 68 KB

    prep_kernel<<<2696, 256, 0, stream>>>(E, W, Eb, Wb, R);
    gemm_a_kernel<<<512, 256, 0, stream>>>(R, Eb, T0, T1);
    gemm_b_kernel<<<512, 256, 0, stream>>>(T0, T1, Wb, out);
}